// Round 5
// baseline (26.084 us; speedup 1.0000x reference)
//
#include <hip/hip_runtime.h>

#define NB 4
#define NS 1024
#define NE 128
#define NH 16
#define ND 8

typedef __attribute__((ext_vector_type(4))) _Float16 half4v;
typedef __attribute__((ext_vector_type(8))) _Float16 half8v;
typedef __attribute__((ext_vector_type(2))) _Float16 half2v;
typedef __attribute__((ext_vector_type(4))) float float4v;

// sqrt(1/sqrt(8)): both QK^T operands carry this -> MFMA out = (k.q)/sqrt(8),
// consumed by __expf (native v_mul_f32(log2e) + v_exp_f32 — never libm).
#define SQRT_ALPHA 0.59460355750136053f

// ---------------------------------------------------------------------------
// Fused quantum-layer + self-attention via f16 MFMA.
// proj[0]=g1*...*g7, proj[w]=g0*...*gw with g_j=cos(x_j+phi_j)  (CNOTs only
// permute a product distribution -> closed form; verified in round 1).
// S^T = K.Q^T via mfma 16x16x16: lane holds P[q=l&15][keys (l>>4)*4+r] ->
// exactly the PV A-fragment after exp+cvt_pkrtz (no LDS bounce for P).
// V staged transposed with a ones-row (col 8 of output = softmax denom);
// lanes e>8 clamp to the ones-row (broadcast; their output cols are unread).
// Two independent key-half streams (ILP across MFMA/exp latency).
// grid = 64 heads x 8 q-tiles(128q); block 512 thr = 8 waves x 16 queries.
// ---------------------------------------------------------------------------
__global__ __launch_bounds__(512)
void qattn_kernel(const float* __restrict__ x, const float* __restrict__ phi,
                  float* __restrict__ aout)
{
    __shared__ __align__(16) _Float16 Klds[NS][8];    // 16 KB, scaled by SQRT_ALPHA
    __shared__ __align__(16) _Float16 Vt[9][1036];    // 18.2 KB: rows0-7 raw k, row8 ones

    const int t    = threadIdx.x;
    const int blk  = blockIdx.x;
    const int qt   = blk & 7;          // 128-query tile
    const int bh   = blk >> 3;
    const int b    = bh >> 4;
    const int h    = bh & 15;
    const int lane = t & 63;
    const int w    = t >> 6;

    const float ph0 = phi[0], ph1 = phi[1], ph2 = phi[2], ph3 = phi[3];
    const float ph4 = phi[4], ph5 = phi[5], ph6 = phi[6], ph7 = phi[7];

    // ---- stage K (scaled) and V^T (raw + ones row); both rows' loads issued first ----
    const float* xb = x + ((size_t)b * NS) * NE + h * ND;
    const int k0 = t, k1 = t + 512;
    float4 xa0 = *(const float4*)(xb + (size_t)k0 * NE);
    float4 xc0 = *(const float4*)(xb + (size_t)k0 * NE + 4);
    float4 xa1 = *(const float4*)(xb + (size_t)k1 * NE);
    float4 xc1 = *(const float4*)(xb + (size_t)k1 * NE + 4);

#pragma unroll
    for (int half = 0; half < 2; ++half) {
        const int k = half ? k1 : k0;
        const float4 xa = half ? xa1 : xa0;
        const float4 xc = half ? xc1 : xc0;
        float g0 = __cosf(xa.x + ph0), g1 = __cosf(xa.y + ph1);
        float g2 = __cosf(xa.z + ph2), g3 = __cosf(xa.w + ph3);
        float g4 = __cosf(xc.x + ph4), g5 = __cosf(xc.y + ph5);
        float g6 = __cosf(xc.z + ph6), g7 = __cosf(xc.w + ph7);
        float s7 = g7, s6 = s7 * g6, s5 = s6 * g5, s4 = s5 * g4, s3 = s4 * g3, s2 = s3 * g2;
        float v0 = s2 * g1;                         // wire 0 expectation
        float v1 = g0 * g1, v2 = v1 * g2, v3 = v2 * g3;
        float v4 = v3 * g4, v5 = v4 * g5, v6 = v5 * g6, v7 = v6 * g7;
        half8v row;
        row[0] = (_Float16)(SQRT_ALPHA * v0); row[1] = (_Float16)(SQRT_ALPHA * v1);
        row[2] = (_Float16)(SQRT_ALPHA * v2); row[3] = (_Float16)(SQRT_ALPHA * v3);
        row[4] = (_Float16)(SQRT_ALPHA * v4); row[5] = (_Float16)(SQRT_ALPHA * v5);
        row[6] = (_Float16)(SQRT_ALPHA * v6); row[7] = (_Float16)(SQRT_ALPHA * v7);
        *(half8v*)&Klds[k][0] = row;
        Vt[0][k] = (_Float16)v0; Vt[1][k] = (_Float16)v1;
        Vt[2][k] = (_Float16)v2; Vt[3][k] = (_Float16)v3;
        Vt[4][k] = (_Float16)v4; Vt[5][k] = (_Float16)v5;
        Vt[6][k] = (_Float16)v6; Vt[7][k] = (_Float16)v7;
        Vt[8][k] = (_Float16)1.0f;
    }
    __syncthreads();

    const int e = lane & 15;
    const int g = lane >> 4;

    // Q fragment (B operand of S^T): B[kd][q], kd=(l>>4)*4+j, q=l&15.
    // Lanes >=32 cover kd 8..15 -> zero (kills garbage K products too).
    half4v qf = (half4v)(_Float16)0.0f;
    if (lane < 32) {
        int qrow = qt * 128 + w * 16 + e;
        qf = *(const half4v*)&Klds[qrow][g * 4];
    }

    const _Float16* kp = &Klds[e][(g & 1) * 4];        // A: K[t*16+(l&15)][(l>>4)*4+j]
    const int ecl = (e > 8) ? 8 : e;                   // clamp: cols 9..15 unread
    const _Float16* vp = &Vt[ecl][g * 4];              // B_V: V[t*16+(l>>4)*4+j][e]

    float4v accA = (float4v)0.0f;
    float4v accB = (float4v)0.0f;
    const float4v zero = (float4v)0.0f;

    // Two independent streams: keys [0,512) and [512,1024).
#pragma unroll 4
    for (int tt = 0; tt < 32; ++tt) {
        half4v kfA = *(const half4v*)(kp + tt * 128);
        half4v kfB = *(const half4v*)(kp + (tt + 32) * 128);
        half4v vfA = *(const half4v*)(vp + tt * 16);
        half4v vfB = *(const half4v*)(vp + (tt + 32) * 16);
        float4v sA = __builtin_amdgcn_mfma_f32_16x16x16f16(kfA, qf, zero, 0, 0, 0);
        float4v sB = __builtin_amdgcn_mfma_f32_16x16x16f16(kfB, qf, zero, 0, 0, 0);
        float pA0 = __expf(sA[0]), pA1 = __expf(sA[1]);
        float pA2 = __expf(sA[2]), pA3 = __expf(sA[3]);
        float pB0 = __expf(sB[0]), pB1 = __expf(sB[1]);
        float pB2 = __expf(sB[2]), pB3 = __expf(sB[3]);
        half2v loA = __builtin_bit_cast(half2v, __builtin_amdgcn_cvt_pkrtz(pA0, pA1));
        half2v hiA = __builtin_bit_cast(half2v, __builtin_amdgcn_cvt_pkrtz(pA2, pA3));
        half2v loB = __builtin_bit_cast(half2v, __builtin_amdgcn_cvt_pkrtz(pB0, pB1));
        half2v hiB = __builtin_bit_cast(half2v, __builtin_amdgcn_cvt_pkrtz(pB2, pB3));
        half4v paA = __builtin_shufflevector(loA, hiA, 0, 1, 2, 3);
        half4v paB = __builtin_shufflevector(loB, hiB, 0, 1, 2, 3);
        accA = __builtin_amdgcn_mfma_f32_16x16x16f16(paA, vfA, accA, 0, 0, 0);
        accB = __builtin_amdgcn_mfma_f32_16x16x16f16(paB, vfB, accB, 0, 0, 0);
    }

    float4v acc = accA + accB;

    // ---- normalize by column 8 (softmax denom) and store ----
    const int src = (lane & 48) | 8;
    float o0, o1, o2, o3;
    {
        float d0 = __shfl(acc[0], src, 64);
        float d1 = __shfl(acc[1], src, 64);
        float d2 = __shfl(acc[2], src, 64);
        float d3 = __shfl(acc[3], src, 64);
        o0 = acc[0] / d0; o1 = acc[1] / d1; o2 = acc[2] / d2; o3 = acc[3] / d3;
    }
    if (e < 8) {
        size_t rbase = (size_t)(b * NS + qt * 128 + w * 16 + g * 4);
        float* op = aout + rbase * NE + h * ND + e;
        op[0 * NE] = o0;
        op[1 * NE] = o1;
        op[2 * NE] = o2;
        op[3 * NE] = o3;
    }
}

// ---------------------------------------------------------------------------
// out = A @ W^T + b, in place (block reads only the 8 rows it writes).
// 512 blocks x 256 thr (2 waves/SIMD). W transposed-staged in two 64-col halves.
// ---------------------------------------------------------------------------
__global__ __launch_bounds__(256)
void proj_kernel(const float* __restrict__ A, const float* __restrict__ W,
                 const float* __restrict__ bias, float* __restrict__ out)
{
    __shared__ float Wt[64][NE + 4];   // transposed half of W, padded
    __shared__ float As[8][NE];

    const int t  = threadIdx.x;
    const int r0 = blockIdx.x * 8;

    for (int i = t; i < 8 * NE; i += 256) {
        As[i >> 7][i & 127] = A[(size_t)(r0 + (i >> 7)) * NE + (i & 127)];
    }

    const int c4 = (t & 31) * 4;
    const int rg = t >> 5;                     // row r0+rg
    float acc0 = 0, acc1 = 0, acc2 = 0, acc3 = 0;

    for (int eh = 0; eh < 2; ++eh) {
        if (eh) __syncthreads();               // previous half fully consumed
        for (int i = t; i < NE * 64; i += 256) {
            int c = i >> 6;
            int e = i & 63;
            Wt[e][c] = W[c * NE + eh * 64 + e];
        }
        __syncthreads();
#pragma unroll 8
        for (int e = 0; e < 64; ++e) {
            float4 wv = *(const float4*)&Wt[e][c4];
            float av = As[rg][eh * 64 + e];
            acc0 += av * wv.x; acc1 += av * wv.y;
            acc2 += av * wv.z; acc3 += av * wv.w;
        }
    }

    float4 bv = *(const float4*)&bias[c4];
    float4 o = make_float4(acc0 + bv.x, acc1 + bv.y, acc2 + bv.z, acc3 + bv.w);
    *(float4*)(out + (size_t)(r0 + rg) * NE + c4) = o;
}

extern "C" void kernel_launch(void* const* d_in, const int* in_sizes, int n_in,
                              void* d_out, int out_size, void* d_ws, size_t ws_size,
                              hipStream_t stream)
{
    (void)in_sizes; (void)n_in; (void)out_size; (void)d_ws; (void)ws_size;
    const float* x   = (const float*)d_in[0];
    const float* phi = (const float*)d_in[1];
    const float* W   = (const float*)d_in[2];
    const float* b   = (const float*)d_in[3];
    float* out = (float*)d_out;

    qattn_kernel<<<dim3(NB * NH * 8), dim3(512), 0, stream>>>(x, phi, out);
    proj_kernel<<<dim3(NB * NS / 8), dim3(256), 0, stream>>>(out, W, b, out);
}

// Round 6
// 24.183 us; speedup vs baseline: 1.0786x; 1.0786x over previous
//
#include <hip/hip_runtime.h>

#define NB 4
#define NS 1024
#define NE 128
#define NH 16
#define ND 8

typedef __attribute__((ext_vector_type(4))) _Float16 half4v;
typedef __attribute__((ext_vector_type(8))) _Float16 half8v;
typedef __attribute__((ext_vector_type(2))) _Float16 half2v;
typedef __attribute__((ext_vector_type(4))) float float4v;

#if __has_builtin(__builtin_amdgcn_exp2f)
#define EXP2F(x) __builtin_amdgcn_exp2f(x)
#else
#define EXP2F(x) exp2f(x)
#endif

// sqrt(log2(e)/sqrt(8)): both QK^T operands carry this -> MFMA out feeds exp2 directly
#define SQRT_ALPHA 0.71423656f

// ---------------------------------------------------------------------------
// Fused quantum-layer + self-attention via f16 MFMA, key-split for occupancy.
// proj[0]=g1*...*g7, proj[w]=g0*...*gw with g_j=cos(x_j+phi_j)  (CNOTs only
// permute a product distribution -> closed form; verified in round 1).
// S^T = K.Q^T via mfma 16x16x16: lane holds P[q=l&15][keys (l>>4)*4+r] ->
// exactly the PV A-fragment after exp2+cvt_pkrtz (no LDS bounce for P).
// V staged transposed with a ones-row (col 8 of output = softmax denom).
// Block = 1024 thr = 16 waves: wave w handles q-subtile (w&7), key half (w>>3).
// Key-half partials (unnormalized, incl. denom col) combined via LDS scratch.
// 32 waves/CU resident (2 blocks x 16 waves) = 2x round-5 occupancy.
// ---------------------------------------------------------------------------
__global__ __launch_bounds__(1024)
void qattn_kernel(const float* __restrict__ x, const float* __restrict__ phi,
                  float* __restrict__ aout)
{
    __shared__ __align__(16) _Float16 Klds[NS][8];    // 16 KB, scaled by SQRT_ALPHA
    __shared__ __align__(16) _Float16 Vt[9][1036];    // 18.2 KB: rows0-7 raw k, row8 ones
    __shared__ __align__(16) float4 scratch[8][64];   // 8 KB: key-half-1 partials

    const int t    = threadIdx.x;
    const int blk  = blockIdx.x;
    const int qt   = blk & 7;          // 128-query tile
    const int bh   = blk >> 3;
    const int b    = bh >> 4;
    const int h    = bh & 15;
    const int lane = t & 63;
    const int w    = t >> 6;           // 0..15
    const int qsub = w & 7;            // 16-query subtile
    const int kh   = w >> 3;           // key half: [kh*512, kh*512+512)

    const float ph0 = phi[0], ph1 = phi[1], ph2 = phi[2], ph3 = phi[3];
    const float ph4 = phi[4], ph5 = phi[5], ph6 = phi[6], ph7 = phi[7];

    // ---- stage K (scaled) and V^T (raw + ones row): one row per thread ----
    {
        const int k = t;
        const float* xr = x + ((size_t)(b * NS + k)) * NE + h * ND;
        float4 xa = *(const float4*)xr;
        float4 xc = *(const float4*)(xr + 4);
        float g0 = __cosf(xa.x + ph0), g1 = __cosf(xa.y + ph1);
        float g2 = __cosf(xa.z + ph2), g3 = __cosf(xa.w + ph3);
        float g4 = __cosf(xc.x + ph4), g5 = __cosf(xc.y + ph5);
        float g6 = __cosf(xc.z + ph6), g7 = __cosf(xc.w + ph7);
        float s7 = g7, s6 = s7 * g6, s5 = s6 * g5, s4 = s5 * g4, s3 = s4 * g3, s2 = s3 * g2;
        float v0 = s2 * g1;                         // wire 0 expectation
        float v1 = g0 * g1, v2 = v1 * g2, v3 = v2 * g3;
        float v4 = v3 * g4, v5 = v4 * g5, v6 = v5 * g6, v7 = v6 * g7;
        half8v row;
        row[0] = (_Float16)(SQRT_ALPHA * v0); row[1] = (_Float16)(SQRT_ALPHA * v1);
        row[2] = (_Float16)(SQRT_ALPHA * v2); row[3] = (_Float16)(SQRT_ALPHA * v3);
        row[4] = (_Float16)(SQRT_ALPHA * v4); row[5] = (_Float16)(SQRT_ALPHA * v5);
        row[6] = (_Float16)(SQRT_ALPHA * v6); row[7] = (_Float16)(SQRT_ALPHA * v7);
        *(half8v*)&Klds[k][0] = row;
        Vt[0][k] = (_Float16)v0; Vt[1][k] = (_Float16)v1;
        Vt[2][k] = (_Float16)v2; Vt[3][k] = (_Float16)v3;
        Vt[4][k] = (_Float16)v4; Vt[5][k] = (_Float16)v5;
        Vt[6][k] = (_Float16)v6; Vt[7][k] = (_Float16)v7;
        Vt[8][k] = (_Float16)1.0f;
    }
    __syncthreads();

    const int e = lane & 15;
    const int g = lane >> 4;

    // Q fragment (B operand of S^T): B[kd][q], kd=(l>>4)*4+j, q=l&15.
    // Lanes >=32 cover kd 8..15 -> zero (kills garbage K products too).
    half4v qf = (half4v)(_Float16)0.0f;
    if (lane < 32) {
        int qrow = qt * 128 + qsub * 16 + e;
        qf = *(const half4v*)&Klds[qrow][g * 4];
    }

    const _Float16* kp = &Klds[kh * 512 + e][(g & 1) * 4];  // A: K[koff+tt*16+(l&15)][(l>>4)*4+j]
    const int ecl = (e > 8) ? 8 : e;                        // clamp: cols 9..15 unread
    const _Float16* vp = &Vt[ecl][kh * 512 + g * 4];        // B_V: V[koff+tt*16+(l>>4)*4+j][e]

    float4v acc = (float4v)0.0f;
    const float4v zero = (float4v)0.0f;

#pragma unroll 4
    for (int tt = 0; tt < 32; ++tt) {
        half4v kf = *(const half4v*)(kp + tt * 128);   // 16 rows * 8 halves
        half4v vf = *(const half4v*)(vp + tt * 16);
        float4v s = __builtin_amdgcn_mfma_f32_16x16x16f16(kf, qf, zero, 0, 0, 0);
        float p0 = EXP2F(s[0]);
        float p1 = EXP2F(s[1]);
        float p2 = EXP2F(s[2]);
        float p3 = EXP2F(s[3]);
        half2v lo = __builtin_bit_cast(half2v, __builtin_amdgcn_cvt_pkrtz(p0, p1));
        half2v hi = __builtin_bit_cast(half2v, __builtin_amdgcn_cvt_pkrtz(p2, p3));
        half4v pa = __builtin_shufflevector(lo, hi, 0, 1, 2, 3);
        acc = __builtin_amdgcn_mfma_f32_16x16x16f16(pa, vf, acc, 0, 0, 0);
    }

    // ---- combine key-half partials: waves 8..15 -> LDS, waves 0..7 add ----
    if (kh == 1) {
        scratch[qsub][lane] = make_float4(acc[0], acc[1], acc[2], acc[3]);
    }
    __syncthreads();
    if (kh == 0) {
        float4 c = scratch[qsub][lane];
        acc[0] += c.x; acc[1] += c.y; acc[2] += c.z; acc[3] += c.w;

        // ---- normalize by column 8 (softmax denom) and store ----
        const int src = (lane & 48) | 8;
        float d0 = __shfl(acc[0], src, 64);
        float d1 = __shfl(acc[1], src, 64);
        float d2 = __shfl(acc[2], src, 64);
        float d3 = __shfl(acc[3], src, 64);
        float o0 = acc[0] / d0, o1 = acc[1] / d1;
        float o2 = acc[2] / d2, o3 = acc[3] / d3;
        if (e < 8) {
            size_t rbase = (size_t)(b * NS + qt * 128 + qsub * 16 + g * 4);
            float* op = aout + rbase * NE + h * ND + e;
            op[0 * NE] = o0;
            op[1 * NE] = o1;
            op[2 * NE] = o2;
            op[3 * NE] = o3;
        }
    }
}

// ---------------------------------------------------------------------------
// out = A @ W^T + b, in place (block reads only the 16 rows it writes).
// 256 blocks x 512 thr (halved W re-staging vs 512-block variant).
// ---------------------------------------------------------------------------
__global__ __launch_bounds__(512)
void proj_kernel(const float* __restrict__ A, const float* __restrict__ W,
                 const float* __restrict__ bias, float* __restrict__ out)
{
    __shared__ float Wt[64][NE + 4];   // transposed half of W, padded (33.8 KB)
    __shared__ float As[16][NE];       // 8 KB

    const int t  = threadIdx.x;
    const int r0 = blockIdx.x * 16;

    for (int i = t; i < 16 * NE; i += 512) {
        As[i >> 7][i & 127] = A[(size_t)(r0 + (i >> 7)) * NE + (i & 127)];
    }

    const int c4 = (t & 31) * 4;
    const int rg = t >> 5;                     // row r0+rg (0..15)
    float acc0 = 0, acc1 = 0, acc2 = 0, acc3 = 0;

    for (int eh = 0; eh < 2; ++eh) {
        if (eh) __syncthreads();               // previous half fully consumed
        for (int i = t; i < NE * 64; i += 512) {
            int c = i >> 6;
            int e = i & 63;
            Wt[e][c] = W[c * NE + eh * 64 + e];
        }
        __syncthreads();
#pragma unroll 8
        for (int e = 0; e < 64; ++e) {
            float4 wv = *(const float4*)&Wt[e][c4];
            float av = As[rg][eh * 64 + e];
            acc0 += av * wv.x; acc1 += av * wv.y;
            acc2 += av * wv.z; acc3 += av * wv.w;
        }
    }

    float4 bv = *(const float4*)&bias[c4];
    float4 o = make_float4(acc0 + bv.x, acc1 + bv.y, acc2 + bv.z, acc3 + bv.w);
    *(float4*)(out + (size_t)(r0 + rg) * NE + c4) = o;
}

extern "C" void kernel_launch(void* const* d_in, const int* in_sizes, int n_in,
                              void* d_out, int out_size, void* d_ws, size_t ws_size,
                              hipStream_t stream)
{
    (void)in_sizes; (void)n_in; (void)out_size; (void)d_ws; (void)ws_size;
    const float* x   = (const float*)d_in[0];
    const float* phi = (const float*)d_in[1];
    const float* W   = (const float*)d_in[2];
    const float* b   = (const float*)d_in[3];
    float* out = (float*)d_out;

    qattn_kernel<<<dim3(NB * NH * 8), dim3(1024), 0, stream>>>(x, phi, out);
    proj_kernel<<<dim3(NB * NS / 16), dim3(512), 0, stream>>>(out, W, b, out);
}